// Round 4
// baseline (91.743 us; speedup 1.0000x reference)
//
#include <hip/hip_runtime.h>
#include <stdint.h>

#define CIN   256
#define COUT  256
#define NE    64
#define RD    64
#define NTOK  2048

typedef __attribute__((ext_vector_type(8))) short bf16x8;
typedef __attribute__((ext_vector_type(4))) float f32x4;

// ---------- helpers ----------
__device__ inline unsigned short f2bf(float f) {
    uint32_t u = __float_as_uint(f);
    uint32_t r = (u + 0x7FFFu + ((u >> 16) & 1u)) >> 16;   // RNE, finite inputs
    return (unsigned short)r;
}

__device__ inline float wave_sum(float v) {
    #pragma unroll
    for (int m = 1; m < 64; m <<= 1) v += __shfl_xor(v, m, 64);
    return v;
}
__device__ inline float wave_max(float v) {
    #pragma unroll
    for (int m = 1; m < 64; m <<= 1) v = fmaxf(v, __shfl_xor(v, m, 64));
    return v;
}

__device__ inline uint32_t rotl32(uint32_t v, int d) { return (v << d) | (v >> (32 - d)); }

// Threefry-2x32, key = (0, 42), matching JAX's threefry2x32 exactly.
__device__ inline void threefry_0_42(uint32_t c0, uint32_t c1, uint32_t& o0, uint32_t& o1) {
    const uint32_t ks0 = 0u, ks1 = 42u, ks2 = 0u ^ 42u ^ 0x1BD11BDAu;
    uint32_t x0 = c0 + ks0, x1 = c1 + ks1;
#define TF_R(r) { x0 += x1; x1 = rotl32(x1, r); x1 ^= x0; }
    TF_R(13) TF_R(15) TF_R(26) TF_R(6)
    x0 += ks1; x1 += ks2 + 1u;
    TF_R(17) TF_R(29) TF_R(16) TF_R(24)
    x0 += ks2; x1 += ks0 + 2u;
    TF_R(13) TF_R(15) TF_R(26) TF_R(6)
    x0 += ks0; x1 += ks1 + 3u;
    TF_R(17) TF_R(29) TF_R(16) TF_R(24)
    x0 += ks1; x1 += ks2 + 4u;
    TF_R(13) TF_R(15) TF_R(26) TF_R(6)
    x0 += ks2; x1 += ks0 + 5u;
#undef TF_R
    o0 = x0; o1 = x1;
}

// ---------- kernel 1: fused [vq | pack_b] ----------
// blocks 0..511: vq (4 tokens/block).  blocks 512..2559: pack.
// Bp layout: 2048 tiles of 4 KB, tile = (ct*8+g)*64 + p where p = e_local*8+kc
// (ct = col-tile of 64 outs, g = e-group, e = g*8+e_local, kc = k-chunk of 32).
// Tile granule qg (16B): n = qg>>2, gp = qg&3 holds k16 = gp ^ ((n>>1)&3)
// -> linear global_load_lds dest + conflict-free ds_read_b128.
__global__ __launch_bounds__(256) void vq_pack_kernel(
    const float* __restrict__ pw, unsigned short* __restrict__ Bp,
    const float* __restrict__ x, const float* __restrict__ mw,
    const float* __restrict__ mb, const float* __restrict__ cent,
    float* __restrict__ resp_out, float* __restrict__ commit_out)
{
    __shared__ float xs[4][CIN];
    __shared__ float cs[NE][RD + 1];
    __shared__ float ksh[4][RD];
    __shared__ float rs[4][NE];

    const int tid = threadIdx.x;

    if (blockIdx.x >= 512) {
        // ---- pack path ----
        int G = (blockIdx.x - 512) * 256 + tid;   // 16B-granule id, 524288 total
        int tile = G >> 8, qg = G & 255;
        int ct = tile >> 9, g = (tile >> 6) & 7, p = tile & 63;
        int e = (g << 3) + (p >> 3), kc = p & 7;
        int n = qg >> 2, gp = qg & 3;
        int k16 = gp ^ ((n >> 1) & 3);
        int o = (ct << 6) + n;
        const float* s = pw + ((size_t)e << 16) + (o << 8) + (kc << 5) + (k16 << 3);
        float4 v0 = *(const float4*)s;
        float4 v1 = *(const float4*)(s + 4);
        ushort4 a, b;
        a.x = f2bf(v0.x); a.y = f2bf(v0.y); a.z = f2bf(v0.z); a.w = f2bf(v0.w);
        b.x = f2bf(v1.x); b.y = f2bf(v1.y); b.z = f2bf(v1.z); b.w = f2bf(v1.w);
        *(ushort4*)(Bp + ((size_t)G << 3)) = a;
        *(ushort4*)(Bp + ((size_t)G << 3) + 4) = b;
        return;
    }

    // ---- vq path (arithmetic identical to round 3) ----
    const int w  = tid >> 6;
    const int t  = tid & 63;
    const int tb = (blockIdx.x << 2) + w;

    ((float4*)xs[w])[t] = ((const float4*)(x + (size_t)tb * CIN))[t];
    #pragma unroll
    for (int j = 0; j < 4; ++j) {
        int fidx = (j << 8) + tid;
        float4 v = ((const float4*)cent)[fidx];
        int row = fidx >> 4, c0 = (fidx & 15) << 2;
        cs[row][c0] = v.x; cs[row][c0 + 1] = v.y; cs[row][c0 + 2] = v.z; cs[row][c0 + 3] = v.w;
    }
    __syncthreads();

    float kr = mb[t];
    const float4* mwr = (const float4*)(mw + (size_t)t * CIN);
    #pragma unroll 8
    for (int j = 0; j < 64; ++j) {
        float4 wv = mwr[j];
        kr += wv.x * xs[w][(j << 2)] + wv.y * xs[w][(j << 2) + 1]
            + wv.z * xs[w][(j << 2) + 2] + wv.w * xs[w][(j << 2) + 3];
    }
    ksh[w][t] = kr;
    float kk = wave_sum(kr * kr);
    __syncthreads();

    float cc = 0.f, dt = 0.f;
    #pragma unroll 8
    for (int r = 0; r < 64; ++r) {
        float cv = cs[t][r];
        cc += cv * cv;
        dt += ksh[w][r] * cv;
    }
    float d = kk + cc - 2.f * dt;

    uint32_t fidx = (uint32_t)((tb << 6) + t);
    uint32_t cnt  = fidx < 65536u ? fidx : fidx - 65536u;
    uint32_t o0, o1;
    threefry_0_42(cnt, cnt + 65536u, o0, o1);
    uint32_t bits = fidx < 65536u ? o0 : o1;
    float uf = __uint_as_float((bits >> 9) | 0x3f800000u) - 1.0f;
    uf = fmaxf(uf, 1.17549435e-38f);
    float g2 = -logf(-logf(uf));

    float sv = g2 - d;                 // TAU = 1
    float mx = wave_max(sv);
    float pz = expf(sv - mx);
    float ps = wave_sum(pz);
    float rv = pz / ps;
    resp_out[(tb << 6) + t] = rv;
    rs[w][t] = rv;
    __syncthreads();

    float q = 0.f;
    #pragma unroll 8
    for (int e2 = 0; e2 < 64; ++e2) q += rs[w][e2] * cs[e2][t];
    float df = kr - q;
    float sq = wave_sum(df * df);
    if (t == 0) commit_out[tb] = sq;
}

// ---------- kernel 2: MoE GEMM ----------
// Block = M128 x N64, 4 m-waves (each 32 rows) share one B panel.
// grid = 16 m-tiles x 4 col-tiles x 8 e-groups = 512, g = bid&7 (XCD swizzle).
// A-frags in registers (af[2][8], reused across all 8 experts). B: 4-slot x 4KB
// LDS ring, counted vmcnt(2) + raw s_barrier per phase (loads in flight across
// barriers). Per expert (8 phases of BK=32): P-acc; epilogue O += resp[m,e]*P.
__device__ inline void stage1(const char* src, char* dst, int lane) {
    __builtin_amdgcn_global_load_lds(
        (const __attribute__((address_space(1))) unsigned int*)(src + (lane << 4)),
        (__attribute__((address_space(3))) unsigned int*)dst, 16, 0, 0);
}

__global__ __launch_bounds__(256, 2) void gemm_kernel(
    const float* __restrict__ x, const float* __restrict__ resp,
    const unsigned short* __restrict__ Bp, float* __restrict__ partial)
{
    __shared__ char Bb[16384];        // 4 slots x 4 KB
    __shared__ float rsh[128][8];     // resp tile [row][e_local]

    const int tid  = threadIdx.x;
    const int lane = tid & 63;
    const int w    = tid >> 6;
    const int lo   = lane & 15, kq = lane >> 4;
    const int bid  = blockIdx.x;
    const int g    = bid & 7, ct = (bid >> 3) & 3, mt = bid >> 5;
    const int m0   = mt << 7;

    // ---- resp tile: 128 rows x 8 experts, one float4 per thread ----
    {
        int idx = tid << 2;                // 0..1020
        int row = idx >> 3, e0 = idx & 7;  // e0 in {0,4}
        float4 rv = *(const float4*)(resp + ((size_t)(m0 + row) << 6) + (g << 3) + e0);
        *(float4*)(&rsh[row][e0]) = rv;
    }

    // ---- A frags in registers: af[mi][kc], rows = m0 + w*32 + mi*16 + lo ----
    bf16x8 af[2][8];
    {
        const float* xb = x + ((size_t)(m0 + (w << 5) + lo) << 8) + (kq << 3);
        #pragma unroll
        for (int mi = 0; mi < 2; ++mi)
            #pragma unroll
            for (int kc = 0; kc < 8; ++kc) {
                const float* s = xb + (mi << 12) + (kc << 5);
                float4 v0 = *(const float4*)s;
                float4 v1 = *(const float4*)(s + 4);
                bf16x8 bv;
                bv[0] = (short)f2bf(v0.x); bv[1] = (short)f2bf(v0.y);
                bv[2] = (short)f2bf(v0.z); bv[3] = (short)f2bf(v0.w);
                bv[4] = (short)f2bf(v1.x); bv[5] = (short)f2bf(v1.y);
                bv[6] = (short)f2bf(v1.z); bv[7] = (short)f2bf(v1.w);
                af[mi][kc] = bv;
            }
    }

    const char* bsrc = (const char*)Bp + ((size_t)((ct << 3) + g) << 18);

    // drain prologue: all vmem consumed (vmcnt clean), rsh ds_writes visible
    asm volatile("s_waitcnt vmcnt(0)" ::: "memory");
    asm volatile("s_waitcnt lgkmcnt(0)" ::: "memory");

    // prefetch phases 0..2 (1 DMA per wave per phase)
    stage1(bsrc + (0 << 12) + (w << 10), Bb + ((0 & 3) << 12) + (w << 10), lane);
    stage1(bsrc + (1 << 12) + (w << 10), Bb + ((1 & 3) << 12) + (w << 10), lane);
    stage1(bsrc + (2 << 12) + (w << 10), Bb + ((2 & 3) << 12) + (w << 10), lane);

    f32x4 P[2][4] = {};
    f32x4 O[2][4] = {};
    const f32x4 z = {};

    for (int p = 0; p < 64; ++p) {
        // counted wait: own phase-p DMA landed; {p+1,p+2} stay in flight
        if (p < 62)       asm volatile("s_waitcnt vmcnt(2)" ::: "memory");
        else if (p == 62) asm volatile("s_waitcnt vmcnt(1)" ::: "memory");
        else              asm volatile("s_waitcnt vmcnt(0)" ::: "memory");
        asm volatile("s_barrier" ::: "memory");   // all waves' phase-p loads done

        char* bt = Bb + ((p & 3) << 12);
        bf16x8 bfr[4];
        #pragma unroll
        for (int ni = 0; ni < 4; ++ni) {
            int n = (ni << 4) + lo;
            bfr[ni] = *(const bf16x8*)(bt + (n << 6) + ((kq ^ ((n >> 1) & 3)) << 4));
        }

        if (p + 3 < 64)   // refill slot (p+3)&3 (safe: post-barrier(p))
            stage1(bsrc + ((size_t)(p + 3) << 12) + (w << 10),
                   Bb + (((p + 3) & 3) << 12) + (w << 10), lane);

        const int kc = p & 7;
        #pragma unroll
        for (int mi = 0; mi < 2; ++mi)
            #pragma unroll
            for (int ni = 0; ni < 4; ++ni)
                P[mi][ni] = __builtin_amdgcn_mfma_f32_16x16x32_bf16(
                    af[mi][kc], bfr[ni], P[mi][ni], 0, 0, 0);

        if ((p & 7) == 7) {   // expert done: O += resp * P; P = 0
            const int el = p >> 3;
            #pragma unroll
            for (int mi = 0; mi < 2; ++mi) {
                float r[4];
                #pragma unroll
                for (int j = 0; j < 4; ++j)
                    r[j] = rsh[(w << 5) + (mi << 4) + (kq << 2) + j][el];
                #pragma unroll
                for (int ni = 0; ni < 4; ++ni) {
                    #pragma unroll
                    for (int j = 0; j < 4; ++j)
                        O[mi][ni][j] += r[j] * P[mi][ni][j];
                    P[mi][ni] = z;
                }
            }
        }
    }

    // ---- write partial [g][2048][256] ----
    float* pout = partial + ((size_t)g << 19)
                + ((size_t)(m0 + (w << 5) + (kq << 2)) << 8) + (ct << 6) + lo;
    #pragma unroll
    for (int mi = 0; mi < 2; ++mi)
        #pragma unroll
        for (int j = 0; j < 4; ++j) {
            float* pr = pout + ((size_t)((mi << 4) + j) << 8);
            #pragma unroll
            for (int ni = 0; ni < 4; ++ni)
                pr[ni << 4] = O[mi][ni][j];
        }
}

// ---------- kernel 3: fused [reduce | loss partials] ----------
__global__ __launch_bounds__(256) void reduce_loss_kernel(
    const float* __restrict__ partial, const float* __restrict__ bias,
    float* __restrict__ out, const float* __restrict__ resp,
    const float* __restrict__ commit_part, float* __restrict__ imp_p,
    float* __restrict__ cm_p)
{
    __shared__ float part[4][64];
    const int t = threadIdx.x;

    if (blockIdx.x < 512) {
        int idx = blockIdx.x * 256 + t;   // float4 id, < 131072
        float4 s = ((const float4*)bias)[idx & 63];
        #pragma unroll
        for (int g = 0; g < 8; ++g) {
            float4 v = ((const float4*)partial)[((size_t)g << 17) + idx];
            s.x += v.x; s.y += v.y; s.z += v.z; s.w += v.w;
        }
        ((float4*)out)[idx] = s;
        return;
    }

    const int b = blockIdx.x - 512;
    const int e = t & 63, grp = t >> 6;
    float s = 0.f;
    #pragma unroll
    for (int j = 0; j < 16; ++j)
        s += resp[(size_t)((b << 6) + (grp << 4) + j) * 64 + e];
    part[grp][e] = s;
    __syncthreads();
    if (t < 64) {
        float v = part[0][t] + part[1][t] + part[2][t] + part[3][t];
        imp_p[(b << 6) + t] = v;
        float cm = commit_part[(b << 6) + t];
        cm = wave_sum(cm);
        if (t == 0) cm_p[b] = cm;
    }
}

// ---------- kernel 4: final loss scalar ----------
__global__ __launch_bounds__(64) void loss_final_kernel(const float* __restrict__ imp_p,
                                                        const float* __restrict__ cm_p,
                                                        float* __restrict__ loss_out)
{
    const int t = threadIdx.x;
    float imp = 0.f;
    #pragma unroll
    for (int b = 0; b < 32; ++b) imp += imp_p[(b << 6) + t];
    float ct = (t < 32) ? cm_p[t] : 0.f;
    ct = wave_sum(ct);
    float tot  = wave_sum(imp);
    float mean = tot * (1.0f / 64.f);
    float dv   = imp - mean;
    float var  = wave_sum(dv * dv) * (1.0f / 63.f);
    if (t == 0) {
        float mse = ct * (1.0f / (float)(NTOK * RD));
        float imp_loss = sqrtf(var) / mean;
        // commitment and kmeans losses are numerically identical forward
        loss_out[0] = (0.25f + 1.0f) * mse + 30.0f * imp_loss;
    }
}

extern "C" void kernel_launch(void* const* d_in, const int* in_sizes, int n_in,
                              void* d_out, int out_size, void* d_ws, size_t ws_size,
                              hipStream_t stream)
{
    const float* x     = (const float*)d_in[0];
    const float* map_w = (const float*)d_in[1];
    const float* map_b = (const float*)d_in[2];
    const float* cent  = (const float*)d_in[3];
    const float* pw_w  = (const float*)d_in[4];
    const float* pw_B  = (const float*)d_in[5];
    float* out = (float*)d_out;

    char* ws = (char*)d_ws;
    float* resp        = (float*)ws;                          // 512 KB
    float* commit      = (float*)(ws + 524288);               // 8 KB
    float* imp_p       = (float*)(ws + 540672);               // 8 KB
    float* cm_p        = (float*)(ws + 557056);               // 128 B
    unsigned short* Bp = (unsigned short*)(ws + (1u << 20));  // 8 MB packed B
    float* partial     = (float*)(ws + (10u << 20));          // 8 * 2 MB = 16 MB

    vq_pack_kernel<<<2560, 256, 0, stream>>>(pw_w, Bp, x, map_w, map_b, cent, resp, commit);
    gemm_kernel<<<512, 256, 0, stream>>>(x, resp, Bp, partial);
    reduce_loss_kernel<<<544, 256, 0, stream>>>(partial, pw_B, out, resp, commit, imp_p, cm_p);
    loss_final_kernel<<<1, 64, 0, stream>>>(imp_p, cm_p, out + NTOK * COUT);
}

// Round 5
// 75.983 us; speedup vs baseline: 1.2074x; 1.2074x over previous
//
#include <hip/hip_runtime.h>
#include <stdint.h>

#define CIN   256
#define COUT  256
#define NE    64
#define RD    64
#define NTOK  2048

typedef __attribute__((ext_vector_type(8))) short bf16x8;
typedef __attribute__((ext_vector_type(4))) float f32x4;

// ---------- helpers ----------
__device__ inline unsigned short f2bf(float f) {
    uint32_t u = __float_as_uint(f);
    uint32_t r = (u + 0x7FFFu + ((u >> 16) & 1u)) >> 16;   // RNE, finite inputs
    return (unsigned short)r;
}

__device__ inline float wave_sum(float v) {
    #pragma unroll
    for (int m = 1; m < 64; m <<= 1) v += __shfl_xor(v, m, 64);
    return v;
}
__device__ inline float wave_max(float v) {
    #pragma unroll
    for (int m = 1; m < 64; m <<= 1) v = fmaxf(v, __shfl_xor(v, m, 64));
    return v;
}

__device__ inline uint32_t rotl32(uint32_t v, int d) { return (v << d) | (v >> (32 - d)); }

// Threefry-2x32, key = (0, 42), matching JAX's threefry2x32 exactly.
__device__ inline void threefry_0_42(uint32_t c0, uint32_t c1, uint32_t& o0, uint32_t& o1) {
    const uint32_t ks0 = 0u, ks1 = 42u, ks2 = 0u ^ 42u ^ 0x1BD11BDAu;
    uint32_t x0 = c0 + ks0, x1 = c1 + ks1;
#define TF_R(r) { x0 += x1; x1 = rotl32(x1, r); x1 ^= x0; }
    TF_R(13) TF_R(15) TF_R(26) TF_R(6)
    x0 += ks1; x1 += ks2 + 1u;
    TF_R(17) TF_R(29) TF_R(16) TF_R(24)
    x0 += ks2; x1 += ks0 + 2u;
    TF_R(13) TF_R(15) TF_R(26) TF_R(6)
    x0 += ks0; x1 += ks1 + 3u;
    TF_R(17) TF_R(29) TF_R(16) TF_R(24)
    x0 += ks1; x1 += ks2 + 4u;
    TF_R(13) TF_R(15) TF_R(26) TF_R(6)
    x0 += ks2; x1 += ks0 + 5u;
#undef TF_R
    o0 = x0; o1 = x1;
}

// ---------- kernel 1: fused [vq | pack_b] ----------
// blocks 0..511: vq (4 tokens/block).  blocks 512..2559: pack.
// Bp layout: 2048 tiles of 4 KB, tile = (ct*8+g)*64 + p where p = e_local*8+kc.
// Tile granule qg (16B): n = qg>>2, gp = qg&3 holds k16 = gp ^ ((n>>1)&3)
// -> linear global_load_lds dest + conflict-free ds_read_b128.
__global__ __launch_bounds__(256) void vq_pack_kernel(
    const float* __restrict__ pw, unsigned short* __restrict__ Bp,
    const float* __restrict__ x, const float* __restrict__ mw,
    const float* __restrict__ mb, const float* __restrict__ cent,
    float* __restrict__ resp_out, float* __restrict__ commit_out)
{
    __shared__ float xs[4][CIN];
    __shared__ float cs[NE][RD + 1];
    __shared__ float ksh[4][RD];
    __shared__ float rs[4][NE];

    const int tid = threadIdx.x;

    if (blockIdx.x >= 512) {
        // ---- pack path ----
        int G = (blockIdx.x - 512) * 256 + tid;   // 16B-granule id, 524288 total
        int tile = G >> 8, qg = G & 255;
        int ct = tile >> 9, g = (tile >> 6) & 7, p = tile & 63;
        int e = (g << 3) + (p >> 3), kc = p & 7;
        int n = qg >> 2, gp = qg & 3;
        int k16 = gp ^ ((n >> 1) & 3);
        int o = (ct << 6) + n;
        const float* s = pw + ((size_t)e << 16) + (o << 8) + (kc << 5) + (k16 << 3);
        float4 v0 = *(const float4*)s;
        float4 v1 = *(const float4*)(s + 4);
        ushort4 a, b;
        a.x = f2bf(v0.x); a.y = f2bf(v0.y); a.z = f2bf(v0.z); a.w = f2bf(v0.w);
        b.x = f2bf(v1.x); b.y = f2bf(v1.y); b.z = f2bf(v1.z); b.w = f2bf(v1.w);
        *(ushort4*)(Bp + ((size_t)G << 3)) = a;
        *(ushort4*)(Bp + ((size_t)G << 3) + 4) = b;
        return;
    }

    // ---- vq path (arithmetic identical to round 3) ----
    const int w  = tid >> 6;
    const int t  = tid & 63;
    const int tb = (blockIdx.x << 2) + w;

    ((float4*)xs[w])[t] = ((const float4*)(x + (size_t)tb * CIN))[t];
    #pragma unroll
    for (int j = 0; j < 4; ++j) {
        int fidx = (j << 8) + tid;
        float4 v = ((const float4*)cent)[fidx];
        int row = fidx >> 4, c0 = (fidx & 15) << 2;
        cs[row][c0] = v.x; cs[row][c0 + 1] = v.y; cs[row][c0 + 2] = v.z; cs[row][c0 + 3] = v.w;
    }
    __syncthreads();

    float kr = mb[t];
    const float4* mwr = (const float4*)(mw + (size_t)t * CIN);
    #pragma unroll 8
    for (int j = 0; j < 64; ++j) {
        float4 wv = mwr[j];
        kr += wv.x * xs[w][(j << 2)] + wv.y * xs[w][(j << 2) + 1]
            + wv.z * xs[w][(j << 2) + 2] + wv.w * xs[w][(j << 2) + 3];
    }
    ksh[w][t] = kr;
    float kk = wave_sum(kr * kr);
    __syncthreads();

    float cc = 0.f, dt = 0.f;
    #pragma unroll 8
    for (int r = 0; r < 64; ++r) {
        float cv = cs[t][r];
        cc += cv * cv;
        dt += ksh[w][r] * cv;
    }
    float d = kk + cc - 2.f * dt;

    uint32_t fidx = (uint32_t)((tb << 6) + t);
    uint32_t cnt  = fidx < 65536u ? fidx : fidx - 65536u;
    uint32_t o0, o1;
    threefry_0_42(cnt, cnt + 65536u, o0, o1);
    uint32_t bits = fidx < 65536u ? o0 : o1;
    float uf = __uint_as_float((bits >> 9) | 0x3f800000u) - 1.0f;
    uf = fmaxf(uf, 1.17549435e-38f);
    float g2 = -logf(-logf(uf));

    float sv = g2 - d;                 // TAU = 1
    float mx = wave_max(sv);
    float pz = expf(sv - mx);
    float ps = wave_sum(pz);
    float rv = pz / ps;
    resp_out[(tb << 6) + t] = rv;
    rs[w][t] = rv;
    __syncthreads();

    float q = 0.f;
    #pragma unroll 8
    for (int e2 = 0; e2 < 64; ++e2) q += rs[w][e2] * cs[e2][t];
    float df = kr - q;
    float sq = wave_sum(df * df);
    if (t == 0) commit_out[tb] = sq;
}

// ---------- kernel 2: MoE GEMM ----------
// Block = M128 x N64, 4 m-waves share one B panel. grid = 16 x 4 x 8 = 512.
// A-frags in registers (af[2][8], STATIC indices only — rule #20). B: 4-slot x
// 4KB LDS ring, counted vmcnt + raw s_barrier per phase. Phase loop FULLY
// unrolled (el 0..7 x kc 0..7) so af index / slot / waits are compile-time.
__device__ inline void stage1(const char* src, char* dst, int lane) {
    __builtin_amdgcn_global_load_lds(
        (const __attribute__((address_space(1))) unsigned int*)(src + (lane << 4)),
        (__attribute__((address_space(3))) unsigned int*)dst, 16, 0, 0);
}

__global__ __launch_bounds__(256, 2) void gemm_kernel(
    const float* __restrict__ x, const float* __restrict__ resp,
    const unsigned short* __restrict__ Bp, float* __restrict__ partial)
{
    __shared__ char Bb[16384];        // 4 slots x 4 KB
    __shared__ float rsh[128][8];     // resp tile [row][e_local]

    const int tid  = threadIdx.x;
    const int lane = tid & 63;
    const int w    = tid >> 6;
    const int lo   = lane & 15, kq = lane >> 4;
    const int bid  = blockIdx.x;
    const int g    = bid & 7, ct = (bid >> 3) & 3, mt = bid >> 5;
    const int m0   = mt << 7;

    // ---- resp tile: 128 rows x 8 experts, one float4 per thread ----
    {
        int idx = tid << 2;                // 0..1020
        int row = idx >> 3, e0 = idx & 7;  // e0 in {0,4}
        float4 rv = *(const float4*)(resp + ((size_t)(m0 + row) << 6) + (g << 3) + e0);
        *(float4*)(&rsh[row][e0]) = rv;
    }

    // ---- A frags in registers: af[mi][kc], rows = m0 + w*32 + mi*16 + lo ----
    bf16x8 af[2][8];
    {
        const float* xb = x + ((size_t)(m0 + (w << 5) + lo) << 8) + (kq << 3);
        #pragma unroll
        for (int mi = 0; mi < 2; ++mi)
            #pragma unroll
            for (int kc = 0; kc < 8; ++kc) {
                const float* s = xb + (mi << 12) + (kc << 5);
                float4 v0 = *(const float4*)s;
                float4 v1 = *(const float4*)(s + 4);
                bf16x8 bv;
                bv[0] = (short)f2bf(v0.x); bv[1] = (short)f2bf(v0.y);
                bv[2] = (short)f2bf(v0.z); bv[3] = (short)f2bf(v0.w);
                bv[4] = (short)f2bf(v1.x); bv[5] = (short)f2bf(v1.y);
                bv[6] = (short)f2bf(v1.z); bv[7] = (short)f2bf(v1.w);
                af[mi][kc] = bv;
            }
    }

    const char* bsrc = (const char*)Bp + ((size_t)((ct << 3) + g) << 18);

    // drain prologue: all vmem consumed (vmcnt clean), rsh ds_writes visible
    asm volatile("s_waitcnt vmcnt(0)" ::: "memory");
    asm volatile("s_waitcnt lgkmcnt(0)" ::: "memory");

    // prefetch phases 0..2 (1 DMA per wave per phase)
    stage1(bsrc + (0 << 12) + (w << 10), Bb + (0 << 12) + (w << 10), lane);
    stage1(bsrc + (1 << 12) + (w << 10), Bb + (1 << 12) + (w << 10), lane);
    stage1(bsrc + (2 << 12) + (w << 10), Bb + (2 << 12) + (w << 10), lane);

    f32x4 P[2][4] = {};
    f32x4 O[2][4] = {};
    const f32x4 z = {};

    #pragma unroll
    for (int el = 0; el < 8; ++el) {
        #pragma unroll
        for (int kc = 0; kc < 8; ++kc) {
            const int p = (el << 3) + kc;     // compile-time constant per body
            // counted wait: own phase-p DMA landed; later phases stay in flight
            if (p < 62)       asm volatile("s_waitcnt vmcnt(2)" ::: "memory");
            else if (p == 62) asm volatile("s_waitcnt vmcnt(1)" ::: "memory");
            else              asm volatile("s_waitcnt vmcnt(0)" ::: "memory");
            asm volatile("s_barrier" ::: "memory");   // all waves' phase-p loads done

            char* bt = Bb + ((p & 3) << 12);
            bf16x8 bfr[4];
            #pragma unroll
            for (int ni = 0; ni < 4; ++ni) {
                int n = (ni << 4) + lo;
                bfr[ni] = *(const bf16x8*)(bt + (n << 6) + ((kq ^ ((n >> 1) & 3)) << 4));
            }

            if (p + 3 < 64)   // refill slot (p+3)&3 = (p-1)&3 (safe post-barrier)
                stage1(bsrc + ((size_t)(p + 3) << 12) + (w << 10),
                       Bb + (((p + 3) & 3) << 12) + (w << 10), lane);

            #pragma unroll
            for (int mi = 0; mi < 2; ++mi)
                #pragma unroll
                for (int ni = 0; ni < 4; ++ni)
                    P[mi][ni] = __builtin_amdgcn_mfma_f32_16x16x32_bf16(
                        af[mi][kc], bfr[ni], P[mi][ni], 0, 0, 0);
        }

        // expert done: O += resp * P; P = 0   (el is compile-time constant)
        #pragma unroll
        for (int mi = 0; mi < 2; ++mi) {
            float r[4];
            #pragma unroll
            for (int j = 0; j < 4; ++j)
                r[j] = rsh[(w << 5) + (mi << 4) + (kq << 2) + j][el];
            #pragma unroll
            for (int ni = 0; ni < 4; ++ni) {
                #pragma unroll
                for (int j = 0; j < 4; ++j)
                    O[mi][ni][j] += r[j] * P[mi][ni][j];
                P[mi][ni] = z;
            }
        }
    }

    // ---- write partial [g][2048][256] ----
    float* pout = partial + ((size_t)g << 19)
                + ((size_t)(m0 + (w << 5) + (kq << 2)) << 8) + (ct << 6) + lo;
    #pragma unroll
    for (int mi = 0; mi < 2; ++mi)
        #pragma unroll
        for (int j = 0; j < 4; ++j) {
            float* pr = pout + ((size_t)((mi << 4) + j) << 8);
            #pragma unroll
            for (int ni = 0; ni < 4; ++ni)
                pr[ni << 4] = O[mi][ni][j];
        }
}

// ---------- kernel 3: fused [reduce | loss partials] ----------
__global__ __launch_bounds__(256) void reduce_loss_kernel(
    const float* __restrict__ partial, const float* __restrict__ bias,
    float* __restrict__ out, const float* __restrict__ resp,
    const float* __restrict__ commit_part, float* __restrict__ imp_p,
    float* __restrict__ cm_p)
{
    __shared__ float part[4][64];
    const int t = threadIdx.x;

    if (blockIdx.x < 512) {
        int idx = blockIdx.x * 256 + t;   // float4 id, < 131072
        float4 s = ((const float4*)bias)[idx & 63];
        #pragma unroll
        for (int g = 0; g < 8; ++g) {
            float4 v = ((const float4*)partial)[((size_t)g << 17) + idx];
            s.x += v.x; s.y += v.y; s.z += v.z; s.w += v.w;
        }
        ((float4*)out)[idx] = s;
        return;
    }

    const int b = blockIdx.x - 512;
    const int e = t & 63, grp = t >> 6;
    float s = 0.f;
    #pragma unroll
    for (int j = 0; j < 16; ++j)
        s += resp[(size_t)((b << 6) + (grp << 4) + j) * 64 + e];
    part[grp][e] = s;
    __syncthreads();
    if (t < 64) {
        float v = part[0][t] + part[1][t] + part[2][t] + part[3][t];
        imp_p[(b << 6) + t] = v;
        float cm = commit_part[(b << 6) + t];
        cm = wave_sum(cm);
        if (t == 0) cm_p[b] = cm;
    }
}

// ---------- kernel 4: final loss scalar ----------
__global__ __launch_bounds__(64) void loss_final_kernel(const float* __restrict__ imp_p,
                                                        const float* __restrict__ cm_p,
                                                        float* __restrict__ loss_out)
{
    const int t = threadIdx.x;
    float imp = 0.f;
    #pragma unroll
    for (int b = 0; b < 32; ++b) imp += imp_p[(b << 6) + t];
    float ct = (t < 32) ? cm_p[t] : 0.f;
    ct = wave_sum(ct);
    float tot  = wave_sum(imp);
    float mean = tot * (1.0f / 64.f);
    float dv   = imp - mean;
    float var  = wave_sum(dv * dv) * (1.0f / 63.f);
    if (t == 0) {
        float mse = ct * (1.0f / (float)(NTOK * RD));
        float imp_loss = sqrtf(var) / mean;
        // commitment and kmeans losses are numerically identical forward
        loss_out[0] = (0.25f + 1.0f) * mse + 30.0f * imp_loss;
    }
}

extern "C" void kernel_launch(void* const* d_in, const int* in_sizes, int n_in,
                              void* d_out, int out_size, void* d_ws, size_t ws_size,
                              hipStream_t stream)
{
    const float* x     = (const float*)d_in[0];
    const float* map_w = (const float*)d_in[1];
    const float* map_b = (const float*)d_in[2];
    const float* cent  = (const float*)d_in[3];
    const float* pw_w  = (const float*)d_in[4];
    const float* pw_B  = (const float*)d_in[5];
    float* out = (float*)d_out;

    char* ws = (char*)d_ws;
    float* resp        = (float*)ws;                          // 512 KB
    float* commit      = (float*)(ws + 524288);               // 8 KB
    float* imp_p       = (float*)(ws + 540672);               // 8 KB
    float* cm_p        = (float*)(ws + 557056);               // 128 B
    unsigned short* Bp = (unsigned short*)(ws + (1u << 20));  // 8 MB packed B
    float* partial     = (float*)(ws + (10u << 20));          // 8 * 2 MB = 16 MB

    vq_pack_kernel<<<2560, 256, 0, stream>>>(pw_w, Bp, x, map_w, map_b, cent, resp, commit);
    gemm_kernel<<<512, 256, 0, stream>>>(x, resp, Bp, partial);
    reduce_loss_kernel<<<544, 256, 0, stream>>>(partial, pw_B, out, resp, commit, imp_p, cm_p);
    loss_final_kernel<<<1, 64, 0, stream>>>(imp_p, cm_p, out + NTOK * COUT);
}